// Round 3
// baseline (113.371 us; speedup 1.0000x reference)
//
#include <hip/hip_runtime.h>
#include <math.h>

// ---------------------------------------------------------------------------
// CategoricalAwareTabularEncoder — design 3 (MFMA phase A)
//
// Algebra: pair-MLP layer-1 factorizes: pairs(i,j)@W1 = emb_i@W1a + emb_j@W1b.
//   U = emb@W1a + b1, V = emb@W1b, Hsum[d] = sum_{i<j} relu(U_i[d]+V_j[d]),
//   combo_sum = Hsum@W2 + P*b2.
// Phase A is ONE 64x192 GEMM (cols: U | V | freq-hidden) done with
// mfma_f32_16x16x32_f16 on 12 waves; cluster distances run concurrently on
// waves 12..15.
// ---------------------------------------------------------------------------

typedef _Float16 h2 __attribute__((ext_vector_type(2)));
typedef _Float16 h8 __attribute__((ext_vector_type(8)));
typedef float f32x4 __attribute__((ext_vector_type(4)));

constexpr int BATCH = 256;
constexpr int NPAIR = 2016;

// LDS map, dword offsets (total 16320 dw = 65280 B)
constexpr int WT_D   = 0;      // Wt[n<192][k<64] f16, row stride 36 dw (72 f16)
constexpr int FF_F   = 0;      //   alias after MFMA: freq_feat f32 [64][10]
constexpr int HS_F   = 640;    //   alias: Hsum f32 [64]
constexpr int CS_F   = 704;    //   alias: combo_sum f32 [10]
constexpr int EMBS_D = 6912;   // emb[s<64][k<64] f16, row stride 36 dw
constexpr int PART_F = 6912;   //   alias after MFMA: phase-B partials [32][64]
constexpr int EMBT_D = 9216;   // embT[k2<32][s<64] h2
constexpr int FHT_D  = 9216;   //   alias after cluster: FH[s][d2] h2, stride 33
constexpr int U2B_D  = 11328;  // U[s][d2] h2, stride 32
constexpr int CF_F   = 11328;  //   alias after phase B: cluster softmax [64][10]
constexpr int V2B_D  = 13376;  // V[s][d2] h2, stride 32
constexpr int DI_F   = 15424;  // distances f32 [64][10]
constexpr int B1F    = 16064;  // comb_b1 f32 [64]
constexpr int FB1F   = 16128;  // freq_b1 f32 [64]
constexpr int FW1LF  = 16192;  // freq_w1 row 64 f32 [64]
constexpr int FQF    = 16256;  // per-token frequency f32 [64]
constexpr int LDS_DW = 16320;

__device__ __forceinline__ h2 pk2(float a, float b) {
#if __has_builtin(__builtin_amdgcn_cvt_pkrtz)
  auto t = __builtin_amdgcn_cvt_pkrtz(a, b);
  return __builtin_bit_cast(h2, t);
#else
  h2 r; r.x = (_Float16)a; r.y = (_Float16)b; return r;
#endif
}

__device__ __forceinline__ h2 hmax2z(h2 a) {
#if __has_builtin(__builtin_elementwise_max)
  h2 z = {(_Float16)0, (_Float16)0};
  return __builtin_elementwise_max(a, z);
#else
  h2 r;
  r.x = a.x > (_Float16)0 ? a.x : (_Float16)0;
  r.y = a.y > (_Float16)0 ? a.y : (_Float16)0;
  return r;
#endif
}

// value held by lane (l+1), valid on even lanes (quad_perm [1,1,3,3])
__device__ __forceinline__ float lane_up1(float v) {
#if __has_builtin(__builtin_amdgcn_update_dpp)
  int r = __builtin_amdgcn_update_dpp(0, __float_as_int(v), 0xF5, 0xF, 0xF, false);
  return __int_as_float(r);
#else
  return __shfl_down(v, 1, 64);
#endif
}

__global__ __launch_bounds__(1024, 4)
void cat_enc_kernel(const int*   __restrict__ ids,
                    const float* __restrict__ emb_table,
                    const float* __restrict__ comb_w1,
                    const float* __restrict__ comb_b1,
                    const float* __restrict__ comb_w2,
                    const float* __restrict__ comb_b2,
                    const float* __restrict__ freq_w1,
                    const float* __restrict__ freq_b1,
                    const float* __restrict__ freq_w2,
                    const float* __restrict__ freq_b2,
                    const float* __restrict__ centers,
                    const float* __restrict__ cat_freq,
                    const float* __restrict__ total_samples,
                    float*       __restrict__ out)
{
  __shared__ __align__(16) unsigned int ldsu[LDS_DW];
  h2*    ldsH = (h2*)ldsu;
  float* ldsf = (float*)ldsu;
  const int tid = threadIdx.x;
  const int b = blockIdx.x, bBase = b * 64;
  const int lane = tid & 63;
  const int wv = __builtin_amdgcn_readfirstlane((int)(tid >> 6));  // wave id

  // ================= S0: stage =============================================
  // Wt[n][k] f16 transpose of the 64x192 weight block (coalesced global reads)
  for (int e = tid; e < 6144; e += 1024) {
    int k2 = e / 192, n = e - k2 * 192;
    int k = 2 * k2;
    float w0, w1;
    if (n < 64)       { w0 = comb_w1[k * 64 + n];            w1 = comb_w1[(k + 1) * 64 + n]; }
    else if (n < 128) { int m = n - 64;  w0 = comb_w1[(64 + k) * 64 + m]; w1 = comb_w1[(65 + k) * 64 + m]; }
    else              { int m = n - 128; w0 = freq_w1[k * 64 + m];        w1 = freq_w1[(k + 1) * 64 + m]; }
    ldsH[WT_D + n * 36 + k2] = pk2(w0, w1);
  }
  // emb gather, both layouts
  {
    int s = tid >> 4, q = tid & 15;
    int id = ids[bBase + s];
    float4 e4 = *(const float4*)(emb_table + (size_t)id * 64 + q * 4);
    h2 p0 = pk2(e4.x, e4.y), p1 = pk2(e4.z, e4.w);
    ldsH[EMBS_D + s * 36 + q * 2]     = p0;
    ldsH[EMBS_D + s * 36 + q * 2 + 1] = p1;
    ldsH[EMBT_D + (q * 2) * 64 + s]     = p0;
    ldsH[EMBT_D + (q * 2 + 1) * 64 + s] = p1;
  }
  // const vectors
  if (tid < 256) {
    int g = tid >> 6, l = tid & 63;
    if (g == 0)      ldsf[B1F + l]   = comb_b1[l];
    else if (g == 1) ldsf[FB1F + l]  = freq_b1[l];
    else if (g == 2) ldsf[FW1LF + l] = freq_w1[64 * 64 + l];
    else             ldsf[FQF + l]   = cat_freq[ids[bBase + l]] / total_samples[0];
  }
  __syncthreads();

  // ================= S1: MFMA (waves 0..11) + cluster (waves 12..15) =======
  f32x4 acc0 = {0.f, 0.f, 0.f, 0.f}, acc1 = acc0, acc2 = acc0, acc3 = acc0;
  const int fi = lane & 15, fq = lane >> 4;
  if (wv < 12) {
    const int mt = wv & 3, ng = wv >> 2;   // ng: 0=U, 1=V, 2=FH
    const int arow = (mt * 16 + fi) * 36 + fq * 4;
    h8 a0 = *(const h8*)(ldsu + EMBS_D + arow);
    h8 a1 = *(const h8*)(ldsu + EMBS_D + arow + 16);
#pragma unroll
    for (int t = 0; t < 4; ++t) {
      const int brow = (ng * 64 + t * 16 + fi) * 36 + fq * 4;
      h8 b0 = *(const h8*)(ldsu + WT_D + brow);
      h8 b1 = *(const h8*)(ldsu + WT_D + brow + 16);
      f32x4 acc = (t == 0) ? acc0 : (t == 1) ? acc1 : (t == 2) ? acc2 : acc3;
      acc = __builtin_amdgcn_mfma_f32_16x16x32_f16(a0, b0, acc, 0, 0, 0);
      acc = __builtin_amdgcn_mfma_f32_16x16x32_f16(a1, b1, acc, 0, 0, 0);
      if (t == 0) acc0 = acc; else if (t == 1) acc1 = acc;
      else if (t == 2) acc2 = acc; else acc3 = acc;
    }
  } else {
    // cluster distances: wave w handles centers {w-12, w-8, w-4(<10)}
    const int cb = wv - 12;
    const int s = lane;
    float d0 = 0.f, d1 = 0.f, d2 = 0.f;
    const float* c0 = centers + cb * 64;        // uniform -> s_load
    const float* c1 = centers + (cb + 4) * 64;
    const float* c2 = centers + (cb + 8) * 64;  // valid only cb<2
#pragma unroll 8
    for (int k2 = 0; k2 < 32; ++k2) {
      h2 e2 = ldsH[EMBT_D + k2 * 64 + s];
      float e0 = (float)e2.x, e1 = (float)e2.y;
      float t0 = e0 - c0[2 * k2], t1 = e1 - c0[2 * k2 + 1];
      d0 = fmaf(t0, t0, fmaf(t1, t1, d0));
      t0 = e0 - c1[2 * k2]; t1 = e1 - c1[2 * k2 + 1];
      d1 = fmaf(t0, t0, fmaf(t1, t1, d1));
      if (cb < 2) {
        t0 = e0 - c2[2 * k2]; t1 = e1 - c2[2 * k2 + 1];
        d2 = fmaf(t0, t0, fmaf(t1, t1, d2));
      }
    }
    ldsf[DI_F + s * 10 + cb]     = sqrtf(d0);
    ldsf[DI_F + s * 10 + cb + 4] = sqrtf(d1);
    if (cb < 2) ldsf[DI_F + s * 10 + cb + 8] = sqrtf(d2);
  }
  __syncthreads();   // cluster done reading EMBT; FHT writes may proceed

  // ================= S2: MFMA epilogue -> U2B / V2B / FHT ==================
  if (wv < 12) {
    const int mt = wv & 3, ng = wv >> 2;
    const bool even = ((lane & 1) == 0);
#pragma unroll
    for (int t = 0; t < 4; ++t) {
      const int col = t * 16 + fi;
      f32x4 acc = (t == 0) ? acc0 : (t == 1) ? acc1 : (t == 2) ? acc2 : acc3;
      float bias = 0.f, fb = 0.f, fw = 0.f;
      if (ng == 0)      bias = ldsf[B1F + col];
      else if (ng == 2) { fb = ldsf[FB1F + col]; fw = ldsf[FW1LF + col]; }
#pragma unroll
      for (int r = 0; r < 4; ++r) {
        const int srow = mt * 16 + fq * 4 + r;
        float v = acc[r];
        if (ng == 0)      v += bias;
        else if (ng == 2) v = fmaxf(v + fb + ldsf[FQF + srow] * fw, 0.f);
        float vn = lane_up1(v);
        if (even) {
          const int d2i = col >> 1;
          if (ng == 0)      ldsH[U2B_D + srow * 32 + d2i] = pk2(v, vn);
          else if (ng == 1) ldsH[V2B_D + srow * 32 + d2i] = pk2(v, vn);
          else              ldsH[FHT_D + srow * 33 + d2i] = pk2(v, vn);
        }
      }
    }
  }
  __syncthreads();

  // ================= S3: phase C (waves 0..9) then phase B (all) ===========
  if (tid < 640) {
    const int s = tid & 63;
    const int f = __builtin_amdgcn_readfirstlane((int)(tid >> 6));
    float acc = freq_b2[f];
#pragma unroll 8
    for (int d2i = 0; d2i < 32; ++d2i) {
      h2 fh = ldsH[FHT_D + s * 33 + d2i];
      acc = fmaf((float)fh.x, freq_w2[(2 * d2i) * 10 + f], acc);      // uniform w
      acc = fmaf((float)fh.y, freq_w2[(2 * d2i + 1) * 10 + f], acc);
    }
    ldsf[FF_F + s * 10 + f] = acc;
  }
  {
    const int dg = tid & 31, g = tid >> 5;
    h2 u2a = ldsH[U2B_D + g * 32 + dg];
    h2 u2b = ldsH[U2B_D + (63 - g) * 32 + dg];
    h2 za = {(_Float16)0, (_Float16)0};
    h2 acca = za, accb = za;
    const int jsplit = 64 - g;
#pragma unroll 4
    for (int j = g + 1; j < 64; ++j) {
      h2 v2 = ldsH[V2B_D + j * 32 + dg];
      acca = acca + hmax2z(u2a + v2);
      if (j >= jsplit) accb = accb + hmax2z(u2b + v2);
    }
    h2 at = acca + accb;
    ldsf[PART_F + g * 64 + 2 * dg]     = (float)at.x;
    ldsf[PART_F + g * 64 + 2 * dg + 1] = (float)at.y;
  }
  __syncthreads();

  // ================= S4: Hsum reduce (wave0) + softmax (wave1) =============
  if (tid < 64) {
    float h = 0.f;
#pragma unroll
    for (int g = 0; g < 32; ++g) h += ldsf[PART_F + g * 64 + tid];
    ldsf[HS_F + tid] = h;
  } else if (tid < 128) {
    const int s = tid - 64;
    float dv[10], dmin = 1e30f;
#pragma unroll
    for (int c = 0; c < 10; ++c) { dv[c] = ldsf[DI_F + s * 10 + c]; dmin = fminf(dmin, dv[c]); }
    float p[10], sum = 0.f;
#pragma unroll
    for (int c = 0; c < 10; ++c) { p[c] = expf(dmin - dv[c]); sum += p[c]; }
    float rs = 1.0f / sum;
#pragma unroll
    for (int c = 0; c < 10; ++c) ldsf[CF_F + s * 10 + c] = p[c] * rs;
  }
  __syncthreads();

  // ================= S5: combo_sum =========================================
  if (tid < 10) {
    float cs = comb_b2[tid] * (float)NPAIR;
#pragma unroll 8
    for (int dd = 0; dd < 64; ++dd)
      cs = fmaf(ldsf[HS_F + dd], comb_w2[dd * 10 + tid], cs);
    ldsf[CS_F + tid] = cs;
  }
  __syncthreads();

  // ================= S6: epilogue ==========================================
  if (tid < 640) {
    const int f = tid % 10;
    float val = (ldsf[FF_F + tid] + ldsf[CS_F + f] + ldsf[CF_F + tid])
              * (1.0f / (float)(NPAIR + 2));
    out[(size_t)b * 640 + tid] = val;
  }
}

extern "C" void kernel_launch(void* const* d_in, const int* in_sizes, int n_in,
                              void* d_out, int out_size, void* d_ws, size_t ws_size,
                              hipStream_t stream) {
  (void)in_sizes; (void)n_in; (void)d_ws; (void)ws_size; (void)out_size;
  const int*   ids        = (const int*)  d_in[0];
  const float* emb_table  = (const float*)d_in[1];
  const float* comb_w1    = (const float*)d_in[2];
  const float* comb_b1    = (const float*)d_in[3];
  const float* comb_w2    = (const float*)d_in[4];
  const float* comb_b2    = (const float*)d_in[5];
  const float* freq_w1    = (const float*)d_in[6];
  const float* freq_b1    = (const float*)d_in[7];
  const float* freq_w2    = (const float*)d_in[8];
  const float* freq_b2    = (const float*)d_in[9];
  const float* centers    = (const float*)d_in[10];
  const float* cat_freq   = (const float*)d_in[11];
  const float* total_samp = (const float*)d_in[12];
  float* out = (float*)d_out;

  hipLaunchKernelGGL(cat_enc_kernel, dim3(BATCH), dim3(1024), 0, stream,
                     ids, emb_table, comb_w1, comb_b1, comb_w2, comb_b2,
                     freq_w1, freq_b1, freq_w2, freq_b2, centers, cat_freq,
                     total_samp, out);
}

// Round 4
// 108.116 us; speedup vs baseline: 1.0486x; 1.0486x over previous
//
#include <hip/hip_runtime.h>
#include <math.h>

// ---------------------------------------------------------------------------
// CategoricalAwareTabularEncoder — design 4
//   K0 (setup): pre-convert weights to f16 into d_ws (Wt 208x64 incl. centers,
//               |c|^2, packed freq_w2).
//   K1 (main): per-batch block (1024 thr). One 64x208 f16 MFMA GEMM computes
//              U | V | freq-hidden | cluster scores. 4 barriers total; tail on
//              one wave. Pair-MLP factorization:
//                U=emb@W1a+b1, V=emb@W1b, Hsum=sum_{i<j} relu(U_i+V_j),
//                combo_sum=Hsum@W2+P*b2.
// ---------------------------------------------------------------------------

typedef _Float16 h2 __attribute__((ext_vector_type(2)));
typedef _Float16 h4 __attribute__((ext_vector_type(4)));
typedef _Float16 h8 __attribute__((ext_vector_type(8)));
typedef float f32x4 __attribute__((ext_vector_type(4)));

constexpr int BATCH = 256;

// d_ws dword offsets
constexpr int WS_WT  = 0;     // Wt[n<208][k2<32] h2  (6656 dw)
constexpr int WS_C2  = 6656;  // |c|^2 f32 [16]
constexpr int WS_W2P = 6672;  // freq_w2 packed h2 [320]

// LDS dword offsets (total 14560 dw = 58240 B)
constexpr int WT_D   = 0;      // Wt[n][k2], row stride 36 dw (7488 dw)
constexpr int PART_F = 0;      //   alias: phase-B partials f32 [32][64]
constexpr int FF_F   = 2048;   //   alias: freq_feat f32 [64][10]
constexpr int CF_F   = 2688;   //   alias: cluster softmax f32 [64][10]
constexpr int DI_F   = 3328;   //   alias: distances f32 [64][10]
constexpr int EMBS_D = 7488;   // emb[s][k2], row stride 36 dw (2304 dw)
constexpr int FHT_D  = 7488;   //   alias: FH[s][d2] h2, row stride 33 (2112 dw)
constexpr int U2B_D  = 9792;   // U[s][d2] h2, stride 32 (2048 dw)
constexpr int V2B_D  = 11840;  // V[s][d2] h2, stride 32 (2048 dw)
constexpr int E2_F   = 13888;  // |e|^2 f32 [64]; alias: Hsum in tail
constexpr int B1F    = 13952;  // comb_b1 [64]
constexpr int FB1F   = 14016;  // freq_b1 [64]
constexpr int FW1L_F = 14080;  // freq_w1 row 64 [64]
constexpr int FQ_F   = 14144;  // token freq [64]
constexpr int W2P_D  = 14208;  // packed freq_w2 h2 [320]
constexpr int C2_F   = 14528;  // |c|^2 [16]
constexpr int CS_F   = 14544;  // combo_sum [16]
constexpr int LDS_DW = 14560;

__device__ __forceinline__ h2 pk2(float a, float b) {
#if __has_builtin(__builtin_amdgcn_cvt_pkrtz)
  auto t = __builtin_amdgcn_cvt_pkrtz(a, b);
  return __builtin_bit_cast(h2, t);
#else
  h2 r; r.x = (_Float16)a; r.y = (_Float16)b; return r;
#endif
}

__device__ __forceinline__ h2 hmax2z(h2 a) {
#if __has_builtin(__builtin_elementwise_max)
  h2 z = {(_Float16)0, (_Float16)0};
  return __builtin_elementwise_max(a, z);
#else
  h2 r;
  r.x = a.x > (_Float16)0 ? a.x : (_Float16)0;
  r.y = a.y > (_Float16)0 ? a.y : (_Float16)0;
  return r;
#endif
}

// value held by lane (l+1), valid on even lanes (quad_perm [1,1,3,3])
__device__ __forceinline__ float lane_up1(float v) {
#if __has_builtin(__builtin_amdgcn_update_dpp)
  int r = __builtin_amdgcn_update_dpp(0, __float_as_int(v), 0xF5, 0xF, 0xF, false);
  return __int_as_float(r);
#else
  return __shfl_down(v, 1, 64);
#endif
}

// ============================ K0: setup ====================================
__global__ __launch_bounds__(256)
void setup_kernel(const float* __restrict__ comb_w1,
                  const float* __restrict__ freq_w1,
                  const float* __restrict__ centers,
                  const float* __restrict__ freq_w2,
                  unsigned int* __restrict__ ws)
{
  int g = blockIdx.x * 256 + threadIdx.x;
  if (g < 6656) {
    int n = g >> 5, k2 = g & 31, k = 2 * k2;
    float w0, w1;
    if (n < 64)       { w0 = comb_w1[k * 64 + n];      w1 = comb_w1[(k + 1) * 64 + n]; }
    else if (n < 128) { int m = n - 64;  w0 = comb_w1[(64 + k) * 64 + m]; w1 = comb_w1[(65 + k) * 64 + m]; }
    else if (n < 192) { int m = n - 128; w0 = freq_w1[k * 64 + m];        w1 = freq_w1[(k + 1) * 64 + m]; }
    else { int c = n - 192;
           w0 = (c < 10) ? centers[c * 64 + k] : 0.f;
           w1 = (c < 10) ? centers[c * 64 + k + 1] : 0.f; }
    ws[WS_WT + g] = __builtin_bit_cast(unsigned int, pk2(w0, w1));
  } else if (g < 6672) {
    int c = g - 6656;
    float acc = 0.f;
    if (c < 10)
      for (int k = 0; k < 64; ++k) { float v = centers[c * 64 + k]; acc = fmaf(v, v, acc); }
    ((float*)ws)[WS_C2 + c] = acc;
  } else if (g < 6992) {
    int i = g - 6672, d2 = i / 10, f = i - d2 * 10;
    ws[WS_W2P + i] = __builtin_bit_cast(unsigned int,
                       pk2(freq_w2[(2 * d2) * 10 + f], freq_w2[(2 * d2 + 1) * 10 + f]));
  }
}

// ============================ K1: main =====================================
__global__ __launch_bounds__(1024, 4)
void cat_enc_kernel(const int*   __restrict__ ids,
                    const float* __restrict__ emb_table,
                    const float* __restrict__ comb_b1,
                    const float* __restrict__ comb_w2,
                    const float* __restrict__ comb_b2,
                    const float* __restrict__ freq_w1,
                    const float* __restrict__ freq_b1,
                    const float* __restrict__ freq_b2,
                    const float* __restrict__ cat_freq,
                    const float* __restrict__ total_samples,
                    const unsigned int* __restrict__ ws,
                    float*       __restrict__ out)
{
  __shared__ __align__(16) unsigned int ldsu[LDS_DW];
  h2*    ldsH = (h2*)ldsu;
  float* ldsf = (float*)ldsu;
  const int tid = threadIdx.x;
  const int b = blockIdx.x, bBase = b * 64;
  const int lane = tid & 63;
  const int wv = __builtin_amdgcn_readfirstlane((int)(tid >> 6));

  // ---------- S0: stage ----------------------------------------------------
  for (int t = tid; t < 1664; t += 1024) {           // Wt: 208 rows x 8 x b128
    int row = t >> 3, c4 = t & 7;
    uint4 v = ((const uint4*)ws)[row * 8 + c4];
    *(uint4*)(ldsu + WT_D + row * 36 + c4 * 4) = v;
  }
  {                                                  // emb gather + |e|^2
    int s = tid >> 4, q = tid & 15;
    int id = ids[bBase + s];
    float4 e4 = *(const float4*)(emb_table + (size_t)id * 64 + q * 4);
    float p = e4.x * e4.x + e4.y * e4.y + e4.z * e4.z + e4.w * e4.w;
    p += __shfl_xor(p, 1, 64); p += __shfl_xor(p, 2, 64);
    p += __shfl_xor(p, 4, 64); p += __shfl_xor(p, 8, 64);
    ldsH[EMBS_D + s * 36 + 2 * q]     = pk2(e4.x, e4.y);
    ldsH[EMBS_D + s * 36 + 2 * q + 1] = pk2(e4.z, e4.w);
    if (q == 0) ldsf[E2_F + s] = p;
  }
  if (tid < 64)       ldsf[B1F + tid] = comb_b1[tid];
  else if (tid < 128) ldsf[FB1F + (tid - 64)] = freq_b1[tid - 64];
  else if (tid < 192) ldsf[FW1L_F + (tid - 128)] = freq_w1[64 * 64 + (tid - 128)];
  else if (tid < 256) { int l = tid - 192;
                        ldsf[FQ_F + l] = cat_freq[ids[bBase + l]] / total_samples[0]; }
  else if (tid < 576) ldsu[W2P_D + (tid - 256)] = ws[WS_W2P + (tid - 256)];
  else if (tid < 592) ldsf[C2_F + (tid - 576)] = ((const float*)ws)[WS_C2 + (tid - 576)];
  __syncthreads();                                   // B1

  // ---------- S1: 64x208 GEMM ----------------------------------------------
  f32x4 acc0 = {0.f, 0.f, 0.f, 0.f}, acc1 = acc0, acc2 = acc0, acc3 = acc0;
  const int fi = lane & 15, fq = lane >> 4;
  if (wv < 12) {                                     // N-tile wv, M-tiles 0..3
    const int brow = WT_D + (wv * 16 + fi) * 36 + fq * 4;
    h8 b0 = *(const h8*)(ldsu + brow);
    h8 b1 = *(const h8*)(ldsu + brow + 16);
#pragma unroll
    for (int m = 0; m < 4; ++m) {
      const int arow = EMBS_D + (m * 16 + fi) * 36 + fq * 4;
      h8 a0 = *(const h8*)(ldsu + arow);
      h8 a1 = *(const h8*)(ldsu + arow + 16);
      f32x4 acc = (m == 0) ? acc0 : (m == 1) ? acc1 : (m == 2) ? acc2 : acc3;
      acc = __builtin_amdgcn_mfma_f32_16x16x32_f16(a0, b0, acc, 0, 0, 0);
      acc = __builtin_amdgcn_mfma_f32_16x16x32_f16(a1, b1, acc, 0, 0, 0);
      if (m == 0) acc0 = acc; else if (m == 1) acc1 = acc;
      else if (m == 2) acc2 = acc; else acc3 = acc;
    }
  } else {                                           // cluster tile, M-tile wv-12
    const int brow = WT_D + (192 + fi) * 36 + fq * 4;
    h8 b0 = *(const h8*)(ldsu + brow);
    h8 b1 = *(const h8*)(ldsu + brow + 16);
    const int m = wv - 12;
    const int arow = EMBS_D + (m * 16 + fi) * 36 + fq * 4;
    h8 a0 = *(const h8*)(ldsu + arow);
    h8 a1 = *(const h8*)(ldsu + arow + 16);
    acc0 = __builtin_amdgcn_mfma_f32_16x16x32_f16(a0, b0, acc0, 0, 0, 0);
    acc0 = __builtin_amdgcn_mfma_f32_16x16x32_f16(a1, b1, acc0, 0, 0, 0);
  }
  __syncthreads();                                   // B2 (EMBS dead after this)

  // ---------- S2: GEMM epilogue -> U2B/V2B/FHT/DI --------------------------
  if (wv < 12) {
    const bool even = ((lane & 1) == 0);
#pragma unroll
    for (int m = 0; m < 4; ++m) {
      f32x4 acc = (m == 0) ? acc0 : (m == 1) ? acc1 : (m == 2) ? acc2 : acc3;
#pragma unroll
      for (int r = 0; r < 4; ++r) {
        const int srow = m * 16 + fq * 4 + r;
        const int col = wv * 16 + fi;                // global col 0..191
        float v = acc[r];
        if (wv < 4)       v += ldsf[B1F + col];
        else if (wv >= 8) v = fmaxf(v + ldsf[FB1F + (col - 128)]
                                     + ldsf[FQ_F + srow] * ldsf[FW1L_F + (col - 128)], 0.f);
        float vn = lane_up1(v);
        if (even) {
          if (wv < 4)      ldsH[U2B_D + srow * 32 + (col >> 1)] = pk2(v, vn);
          else if (wv < 8) ldsH[V2B_D + srow * 32 + ((col - 64) >> 1)] = pk2(v, vn);
          else             ldsH[FHT_D + srow * 33 + ((col - 128) >> 1)] = pk2(v, vn);
        }
      }
    }
  } else if (fi < 10) {                              // distances
    const int m = wv - 12;
#pragma unroll
    for (int r = 0; r < 4; ++r) {
      const int s = m * 16 + fq * 4 + r;
      float d2v = ldsf[E2_F + s] + ldsf[C2_F + fi] - 2.f * acc0[r];
      ldsf[DI_F + s * 10 + fi] = sqrtf(fmaxf(d2v, 0.f));
    }
  }
  __syncthreads();                                   // B3

  // ---------- S3: phase B (waves 0-7) | freq_feat (8-14) | softmax (15) ----
  if (tid < 512) {
    const int g = tid >> 4, t = tid & 15;            // rows {g, 63-g}, d2 {2t,2t+1}
    h4 uA = *(const h4*)&ldsH[U2B_D + g * 32 + 2 * t];
    h4 uB = *(const h4*)&ldsH[U2B_D + (63 - g) * 32 + 2 * t];
    h2 uA0 = {uA.x, uA.y}, uA1 = {uA.z, uA.w};
    h2 uB0 = {uB.x, uB.y}, uB1 = {uB.z, uB.w};
    h2 z = {(_Float16)0, (_Float16)0};
    h2 aA0 = z, aA1 = z, aB0 = z, aB1 = z;
    const int jsplit = 64 - g;
#pragma unroll 4
    for (int j = g + 1; j < 64; ++j) {
      h4 vv = *(const h4*)&ldsH[V2B_D + j * 32 + 2 * t];
      h2 v0 = {vv.x, vv.y}, v1 = {vv.z, vv.w};
      aA0 = aA0 + hmax2z(uA0 + v0);
      aA1 = aA1 + hmax2z(uA1 + v1);
      if (j >= jsplit) {
        aB0 = aB0 + hmax2z(uB0 + v0);
        aB1 = aB1 + hmax2z(uB1 + v1);
      }
    }
    h2 t0 = aA0 + aB0, t1 = aA1 + aB1;
    float4 pw = make_float4((float)t0.x, (float)t0.y, (float)t1.x, (float)t1.y);
    *(float4*)(ldsf + PART_F + g * 64 + 4 * t) = pw;
  } else if (tid < 960) {                            // freq_feat: FF = FH @ w2 + b2
    const int task = tid - 512;
#pragma unroll
    for (int pass = 0; pass < 2; ++pass) {
      const int o = task + pass * 448;
      if (o < 640) {
        const int s = o / 10, f = o - s * 10;
        float acc = freq_b2[f];
#pragma unroll 8
        for (int d2 = 0; d2 < 32; ++d2) {
          h2 fh = ldsH[FHT_D + s * 33 + d2];
          h2 w  = ldsH[W2P_D + d2 * 10 + f];
          acc += (float)fh.x * (float)w.x + (float)fh.y * (float)w.y;
        }
        ldsf[FF_F + o] = acc;
      }
    }
  } else {                                           // softmax over -dist
    const int s = tid - 960;
    float dv[10], dmin = 1e30f;
#pragma unroll
    for (int c = 0; c < 10; ++c) { dv[c] = ldsf[DI_F + s * 10 + c]; dmin = fminf(dmin, dv[c]); }
    float p[10], sum = 0.f;
#pragma unroll
    for (int c = 0; c < 10; ++c) { p[c] = expf(dmin - dv[c]); sum += p[c]; }
    float rs = 1.0f / sum;
#pragma unroll
    for (int c = 0; c < 10; ++c) ldsf[CF_F + s * 10 + c] = p[c] * rs;
  }
  __syncthreads();                                   // B4

  // ---------- tail: wave 0 only (same-wave LDS ordering, no barriers) ------
  if (tid < 64) {
    float hs = 0.f;
#pragma unroll
    for (int g = 0; g < 32; ++g) hs += ldsf[PART_F + g * 64 + tid];
    ldsf[E2_F + tid] = hs;                           // Hsum (E2 dead)
    if (tid < 10) {
      float cs = comb_b2[tid] * 2016.f;
#pragma unroll 8
      for (int d = 0; d < 64; ++d)
        cs = fmaf(ldsf[E2_F + d], comb_w2[d * 10 + tid], cs);
      ldsf[CS_F + tid] = cs;
    }
    const float inv = 1.0f / 2018.f;
#pragma unroll
    for (int m = 0; m < 10; ++m) {
      const int idx = tid + 64 * m;
      const int f = idx % 10;
      float val = (ldsf[FF_F + idx] + ldsf[CS_F + f] + ldsf[CF_F + idx]) * inv;
      out[(size_t)b * 640 + idx] = val;
    }
  }
}

extern "C" void kernel_launch(void* const* d_in, const int* in_sizes, int n_in,
                              void* d_out, int out_size, void* d_ws, size_t ws_size,
                              hipStream_t stream) {
  (void)in_sizes; (void)n_in; (void)ws_size; (void)out_size;
  const int*   ids        = (const int*)  d_in[0];
  const float* emb_table  = (const float*)d_in[1];
  const float* comb_w1    = (const float*)d_in[2];
  const float* comb_b1    = (const float*)d_in[3];
  const float* comb_w2    = (const float*)d_in[4];
  const float* comb_b2    = (const float*)d_in[5];
  const float* freq_w1    = (const float*)d_in[6];
  const float* freq_b1    = (const float*)d_in[7];
  const float* freq_w2    = (const float*)d_in[8];
  const float* freq_b2    = (const float*)d_in[9];
  const float* centers    = (const float*)d_in[10];
  const float* cat_freq   = (const float*)d_in[11];
  const float* total_samp = (const float*)d_in[12];
  float* out = (float*)d_out;
  unsigned int* ws = (unsigned int*)d_ws;

  hipLaunchKernelGGL(setup_kernel, dim3(28), dim3(256), 0, stream,
                     comb_w1, freq_w1, centers, freq_w2, ws);
  hipLaunchKernelGGL(cat_enc_kernel, dim3(BATCH), dim3(1024), 0, stream,
                     ids, emb_table, comb_b1, comb_w2, comb_b2,
                     freq_w1, freq_b1, freq_b2, cat_freq, total_samp, ws, out);
}